// Round 1
// baseline (768.276 us; speedup 1.0000x reference)
//
#include <hip/hip_runtime.h>
#include <hip/hip_bf16.h>
#include <math.h>

// Problem constants
#define N_E      16384
#define E_DIM    64
#define GROUPS   4
#define N_E_G    4096      // codes per group
#define NB       16
#define NH       32
#define NW       32
#define NQ       16384     // B*H*W query vectors
#define HWsz     1024      // H*W

// Output layout (element offsets into d_out, float32)
#define OFF_QUANT   0L
#define SZ_QUANT    4194304L          // 16*256*32*32
#define OFF_VQLOSS  4194304L          // 4
#define OFF_PERP    4194316L          // 1
#define OFF_MINENC  4194317L          // 16384*4096
#define SZ_MINENC   67108864L
#define OFF_IDX     71303181L         // 16384*4
#define OUT_TOTAL   71368717L

// Workspace layout (element offsets into d_ws as float*/int*)
#define WS_EN     0L          // normalized emb [16384][64]
#define WS_EN2    1048576L    // |e|^2 per code [16384]
#define WS_ZN     1064960L    // normalized z, layout [g][d][n] : (g*64+d)*16384+n
#define WS_ZN2    5259264L    // |z|^2 [g][n]
#define WS_HIST   5324800L    // int[4096]
#define WS_IDX3   5328896L    // int[16384]
// total ~5,345,280 elems = ~21.4 MB of ws

// ---------------------------------------------------------------------------
// K0: normalize embedding (one wave per code), store normalized vec + |e|^2
__global__ void norm_emb_kernel(const float* __restrict__ emb,
                                float* __restrict__ en, float* __restrict__ en2) {
    int gid  = blockIdx.x * blockDim.x + threadIdx.x;
    int code = gid >> 6;
    int lane = threadIdx.x & 63;
    if (code >= N_E) return;
    float x = emb[code * 64 + lane];
    float ss = x * x;
    #pragma unroll
    for (int off = 32; off; off >>= 1) ss += __shfl_xor(ss, off, 64);
    float nrm = sqrtf(ss);
    float v = x / fmaxf(nrm, 1e-12f);
    en[code * 64 + lane] = v;
    float s2 = v * v;
    #pragma unroll
    for (int off = 32; off; off >>= 1) s2 += __shfl_xor(s2, off, 64);
    if (lane == 0) en2[code] = s2;
}

// ---------------------------------------------------------------------------
// K1: normalize z. Input layout z[b][c][hw] (c = g*64+d); n = b*1024+hw is
// contiguous per (b,c). Output zn_t[(g*64+d)*16384 + n] (K-major for GEMM).
__global__ void norm_z_kernel(const float* __restrict__ z,
                              float* __restrict__ znt, float* __restrict__ zn2) {
    int n  = blockIdx.x * blockDim.x + threadIdx.x;   // 64 blocks * 256
    int b  = n >> 10;
    int hw = n & 1023;
    long base = (long)b * 262144 + hw;
    #pragma unroll
    for (int g = 0; g < GROUPS; ++g) {
        float ss = 0.f;
        for (int d = 0; d < 64; ++d) {
            float x = z[base + (long)(g * 64 + d) * 1024];
            ss = fmaf(x, x, ss);
        }
        float nrm = sqrtf(ss);
        float mx  = fmaxf(nrm, 1e-12f);
        float s2 = 0.f;
        for (int d = 0; d < 64; ++d) {
            float x = z[base + (long)(g * 64 + d) * 1024];
            float v = x / mx;
            znt[(long)(g * 64 + d) * 16384 + n] = v;
            s2 = fmaf(v, v, s2);
        }
        zn2[g * 16384 + n] = s2;
    }
}

// ---------------------------------------------------------------------------
// K2: per group, tile of 128 queries; loop over 32 code tiles of 128; 8x8
// outer-product per thread; running argmax; write quant + idx (+hist for g=3).
__global__ __launch_bounds__(256, 2)
void vq_argmax_kernel(const float* __restrict__ znt, const float* __restrict__ zn2,
                      const float* __restrict__ en,  const float* __restrict__ en2,
                      float* __restrict__ out, int* __restrict__ idx3,
                      int* __restrict__ hist) {
    __shared__ float As[64][128];    // [k][m]
    __shared__ float Bs[64][132];    // [k][j], padded
    __shared__ float e2s[128];
    __shared__ int   bks[128];

    const int g  = blockIdx.y;
    const int m0 = blockIdx.x * 128;
    const int t  = threadIdx.x;
    const int tx = t & 15;           // query sub-tile (8 queries)
    const int ty = t >> 4;           // code sub-tile (8 codes)

    // Load A tile (reused across all 32 code tiles): 64 rows(k) x 128 cols(m)
    {
        const float* src = znt + (long)g * 64 * 16384 + m0;
        int c4 = (t & 31) * 4;
        int k0 = t >> 5;             // 0..7
        #pragma unroll
        for (int r = 0; r < 8; ++r) {
            int k = k0 + r * 8;
            float4 v = *(const float4*)(src + (long)k * 16384 + c4);
            *(float4*)(&As[k][c4]) = v;
        }
    }
    float zn2v[8];
    #pragma unroll
    for (int i = 0; i < 8; ++i) zn2v[i] = zn2[g * 16384 + m0 + tx * 8 + i];

    float best[8];
    int   bestk[8];
    #pragma unroll
    for (int i = 0; i < 8; ++i) { best[i] = -3.4e38f; bestk[i] = 0; }

    __syncthreads();

    for (int tile = 0; tile < 32; ++tile) {
        int j0 = tile * 128;
        // Stage B tile (transpose to [k][j]) + e2
        {
            int jj = t >> 1, half = t & 1;
            const float* src = en + ((long)(g * N_E_G + j0 + jj)) * 64 + half * 32;
            #pragma unroll
            for (int q = 0; q < 8; ++q) {
                float4 v = *(const float4*)(src + q * 4);
                int d0 = half * 32 + q * 4;
                Bs[d0 + 0][jj] = v.x; Bs[d0 + 1][jj] = v.y;
                Bs[d0 + 2][jj] = v.z; Bs[d0 + 3][jj] = v.w;
            }
            if (t < 128) e2s[t] = en2[g * N_E_G + j0 + t];
        }
        __syncthreads();

        float acc[8][8];
        #pragma unroll
        for (int i = 0; i < 8; ++i)
            #pragma unroll
            for (int j = 0; j < 8; ++j) acc[i][j] = 0.f;

        #pragma unroll 4
        for (int k = 0; k < 64; ++k) {
            float4 a0 = *(const float4*)(&As[k][tx * 8]);
            float4 a1 = *(const float4*)(&As[k][tx * 8 + 4]);
            float4 b0 = *(const float4*)(&Bs[k][ty * 8]);
            float4 b1 = *(const float4*)(&Bs[k][ty * 8 + 4]);
            float a[8] = {a0.x, a0.y, a0.z, a0.w, a1.x, a1.y, a1.z, a1.w};
            float bb[8] = {b0.x, b0.y, b0.z, b0.w, b1.x, b1.y, b1.z, b1.w};
            #pragma unroll
            for (int i = 0; i < 8; ++i)
                #pragma unroll
                for (int j = 0; j < 8; ++j)
                    acc[i][j] = fmaf(a[i], bb[j], acc[i][j]);
        }

        // epilogue: d = (2*dot - |z|^2) - |e|^2, running first-wins argmax
        #pragma unroll
        for (int j = 0; j < 8; ++j) {
            int   kidx = j0 + ty * 8 + j;
            float e2   = e2s[ty * 8 + j];
            #pragma unroll
            for (int i = 0; i < 8; ++i) {
                float d = (2.0f * acc[i][j] - zn2v[i]) - e2;
                if (d > best[i]) { best[i] = d; bestk[i] = kidx; }
            }
        }
        __syncthreads();   // before Bs is overwritten next tile
    }

    // Cross-thread reduction over ty (16 candidates per query), ties -> min k
    float* rv = (float*)&As[0][0];   // reuse LDS
    int*   rk = (int*)&Bs[0][0];
    #pragma unroll
    for (int i = 0; i < 8; ++i) {
        int m = tx * 8 + i;
        rv[m * 16 + ty] = best[i];
        rk[m * 16 + ty] = bestk[i];
    }
    __syncthreads();

    if (t < 128) {
        float bv = rv[t * 16];
        int   bk = rk[t * 16];
        #pragma unroll
        for (int y = 1; y < 16; ++y) {
            float v = rv[t * 16 + y];
            int   k = rk[t * 16 + y];
            if (v > bv || (v == bv && k < bk)) { bv = v; bk = k; }
        }
        bks[t] = bk;
        int n = m0 + t;
        out[OFF_IDX + (long)n * 4 + g] = (float)bk;
        if (g == 3) {
            idx3[n] = bk;
            atomicAdd(&hist[bk], 1);
        }
    }
    __syncthreads();

    // quant write: quant[b, g*64+d, hw] = en[g, bk, d]; coalesced along n
    for (int i = t; i < 128 * 64; i += 256) {
        int d = i >> 7;
        int m = i & 127;
        int n = m0 + m;
        int b = n >> 10, hw = n & 1023;
        out[OFF_QUANT + (long)b * 262144 + (long)(g * 64 + d) * 1024 + hw] =
            en[((long)(g * N_E_G + bks[m])) * 64 + d];
    }
}

// ---------------------------------------------------------------------------
// K3a: zero-fill [OFF_VQLOSS, OFF_IDX) : losses/usage/perp slot + min_encodings
__global__ void fill_zero_kernel(float* __restrict__ out) {
    const long n  = OFF_IDX - OFF_VQLOSS;      // 67,108,877
    const long n4 = n >> 2;                    // 16,777,219 float4s (tail 1)
    float4* p4 = (float4*)(out + OFF_VQLOSS);
    long i = (long)blockIdx.x * blockDim.x + threadIdx.x;
    long stride = (long)gridDim.x * blockDim.x;
    float4 z = {0.f, 0.f, 0.f, 0.f};
    for (long j = i; j < n4; j += stride) p4[j] = z;
    if (i == 0) {
        float* p = out + OFF_VQLOSS;
        for (long j = n4 * 4; j < n; ++j) p[j] = 0.f;
    }
}

// K3b: scatter the ones into min_encodings
__global__ void scatter_ones_kernel(const int* __restrict__ idx3,
                                    float* __restrict__ out) {
    int r = blockIdx.x * blockDim.x + threadIdx.x;
    if (r < NQ) out[OFF_MINENC + (long)r * N_E_G + idx3[r]] = 1.0f;
}

// K3c: perplexity from histogram
__global__ void perplexity_kernel(const int* __restrict__ hist,
                                  float* __restrict__ out) {
    __shared__ float s[256];
    int t = threadIdx.x;
    float acc = 0.f;
    for (int k = t; k < N_E_G; k += 256) {
        float p = (float)hist[k] * (1.0f / 16384.0f);
        acc += p * logf(p + 1e-10f);
    }
    s[t] = acc;
    __syncthreads();
    for (int o = 128; o; o >>= 1) {
        if (t < o) s[t] += s[t + o];
        __syncthreads();
    }
    if (t == 0) out[OFF_PERP] = expf(-s[0]);
}

// ---------------------------------------------------------------------------
extern "C" void kernel_launch(void* const* d_in, const int* in_sizes, int n_in,
                              void* d_out, int out_size, void* d_ws, size_t ws_size,
                              hipStream_t stream) {
    const float* z_groups = (const float*)d_in[0];
    const float* emb      = (const float*)d_in[1];
    float* out = (float*)d_out;
    float* ws  = (float*)d_ws;

    float* en   = ws + WS_EN;
    float* en2  = ws + WS_EN2;
    float* znt  = ws + WS_ZN;
    float* zn2  = ws + WS_ZN2;
    int*   hist = (int*)(ws + WS_HIST);
    int*   idx3 = (int*)(ws + WS_IDX3);

    // independent output zero-fill (268 MB; ~50us @ 6 TB/s)
    fill_zero_kernel<<<1024, 256, 0, stream>>>(out);

    norm_emb_kernel<<<N_E / 4, 256, 0, stream>>>(emb, en, en2);
    norm_z_kernel<<<NQ / 256, 256, 0, stream>>>(z_groups, znt, zn2);
    hipMemsetAsync(hist, 0, N_E_G * sizeof(int), stream);

    dim3 grid(NQ / 128, GROUPS);
    vq_argmax_kernel<<<grid, 256, 0, stream>>>(znt, zn2, en, en2, out, idx3, hist);

    scatter_ones_kernel<<<NQ / 256, 256, 0, stream>>>(idx3, out);
    perplexity_kernel<<<1, 256, 0, stream>>>(hist, out);
}

// Round 2
// 480.959 us; speedup vs baseline: 1.5974x; 1.5974x over previous
//
#include <hip/hip_runtime.h>
#include <hip/hip_bf16.h>
#include <math.h>

// Problem constants
#define N_E      16384
#define E_DIM    64
#define GROUPS   4
#define N_E_G    4096
#define NQ       16384     // B*H*W query vectors

// Output layout (element offsets into d_out, float32)
#define OFF_QUANT   0L
#define OFF_VQLOSS  4194304L
#define OFF_PERP    4194316L
#define OFF_MINENC  4194317L
#define OFF_IDX     71303181L

// Workspace layout (element offsets into d_ws as float*/int*)
#define WS_EN     0L          // normalized emb fp32 [4][4096][64]
#define WS_EN2    1048576L    // |e|^2 per code [16384]
#define WS_ENHI   1064960L    // bf16(en) as ushort [4][4096][64] -> 524288 floats
#define WS_ZNR    1589248L    // normalized z fp32 [g][q][64]
#define WS_ZHI    5783552L    // bf16(zn) ushort [g][q][64] -> 2097152 floats
#define WS_HIST   7880704L    // int[4096]
#define WS_IDX3   7884800L    // int[16384]
// total 7,901,184 floats = 31.6 MB

typedef float  float4v  __attribute__((ext_vector_type(4)));
typedef short  short8   __attribute__((ext_vector_type(8)));

static __device__ __forceinline__ ushort f2bf(float x) {
    __hip_bfloat16 h = __float2bfloat16(x);   // RN
    union { __hip_bfloat16 h; ushort u; } cv; cv.h = h;
    return cv.u;
}

// ---------------------------------------------------------------------------
// K0: normalize embedding (one wave per code): en fp32, en2, en_hi bf16
__global__ void norm_emb_kernel(const float* __restrict__ emb,
                                float* __restrict__ en, float* __restrict__ en2,
                                ushort* __restrict__ ehi) {
    int gid  = blockIdx.x * blockDim.x + threadIdx.x;
    int code = gid >> 6;
    int lane = threadIdx.x & 63;
    if (code >= N_E) return;
    float x = emb[code * 64 + lane];
    float ss = x * x;
    #pragma unroll
    for (int off = 32; off; off >>= 1) ss += __shfl_xor(ss, off, 64);
    float v = x / fmaxf(sqrtf(ss), 1e-12f);
    en[code * 64 + lane]  = v;
    ehi[code * 64 + lane] = f2bf(v);
    float s2 = v * v;
    #pragma unroll
    for (int off = 32; off; off >>= 1) s2 += __shfl_xor(s2, off, 64);
    if (lane == 0) en2[code] = s2;
}

// ---------------------------------------------------------------------------
// K1: normalize z -> znr fp32 [g][q][64] + zhi bf16 [g][q][64], coalesced writes.
__global__ void norm_z_kernel(const float* __restrict__ z,
                              float* __restrict__ znr, ushort* __restrict__ zhi) {
    __shared__ float rden[256];
    const int g  = blockIdx.y;
    const int n0 = blockIdx.x * 256;
    const int t  = threadIdx.x;

    // phase A: per-query norm (coalesced along hw)
    {
        int n = n0 + t, b = n >> 10, hw = n & 1023;
        const float* src = z + (size_t)b * 262144 + (size_t)g * 65536 + hw;
        float ss = 0.f;
        for (int d = 0; d < 64; ++d) {
            float x = src[(size_t)d * 1024];
            ss = fmaf(x, x, ss);
        }
        rden[t] = fmaxf(sqrtf(ss), 1e-12f);
    }
    __syncthreads();

    // phase B: transposed, coalesced writes. thread i -> (ql, d4 block of 4)
    for (int i = t; i < 256 * 16; i += 256) {
        int ql = i >> 4, d4 = (i & 15) * 4;
        int n = n0 + ql, b = n >> 10, hw = n & 1023;
        const float* src = z + (size_t)b * 262144 + (size_t)g * 65536 + hw;
        float den = rden[ql];
        float v0 = src[(size_t)(d4 + 0) * 1024] / den;
        float v1 = src[(size_t)(d4 + 1) * 1024] / den;
        float v2 = src[(size_t)(d4 + 2) * 1024] / den;
        float v3 = src[(size_t)(d4 + 3) * 1024] / den;
        float4v f = {v0, v1, v2, v3};
        *(float4v*)(znr + ((size_t)g * NQ + n) * 64 + d4) = f;
        ushort u0 = f2bf(v0), u1 = f2bf(v1), u2 = f2bf(v2), u3 = f2bf(v3);
        ushort4 u = {u0, u1, u2, u3};
        *(ushort4*)(zhi + ((size_t)g * NQ + n) * 64 + d4) = u;
    }
}

// ---------------------------------------------------------------------------
// K2: bf16-hi MFMA candidate generation + exact fp32 rescore + outputs.
// Block: 256 thr = 4 waves; 128 queries x 4096 codes (32 tiles of 128).
// wave: qhalf = wave&1 (64 queries), chalf = wave>>1 (64 codes of the tile).
// TAU >= 2*E, E = worst-case |dot - bf16hi-dot| <= 2*2^-8*(1+eps) = 7.83e-3.
#define CAP  64
#define TAU  0.017f
__global__ __launch_bounds__(256, 2)
void vq_cand_kernel(const ushort* __restrict__ zhi, const ushort* __restrict__ ehi,
                    const float* __restrict__ znr, const float* __restrict__ en,
                    const float* __restrict__ en2,
                    float* __restrict__ out, int* __restrict__ idx3,
                    int* __restrict__ hist) {
    __shared__ ushort eA[128 * 64];      // 16 KB, xor-swizzled chunks
    __shared__ int    cnt[128];
    __shared__ int    cand[128 * CAP];   // 32 KB
    __shared__ int    bks[128];

    const int g  = blockIdx.y;
    const int q0 = blockIdx.x * 128;
    const int t  = threadIdx.x;
    const int wave = t >> 6, lane = t & 63;
    const int l15 = lane & 15, quad = lane >> 4;
    const int qhalf = wave & 1, chalf = wave >> 1;

    if (t < 128) cnt[t] = 0;

    // B-frags (queries, bf16-hi): lane holds z[q][quad*8 + ks*32 .. +7]
    short8 bfrag[4][2];
    {
        const ushort* zq = zhi + ((size_t)g * NQ + q0 + qhalf * 64 + l15) * 64 + quad * 8;
        #pragma unroll
        for (int u = 0; u < 4; ++u)
            #pragma unroll
            for (int ks = 0; ks < 2; ++ks)
                bfrag[u][ks] = *(const short8*)(zq + (size_t)u * 16 * 64 + ks * 32);
    }

    float Mrun[4];
    #pragma unroll
    for (int u = 0; u < 4; ++u) Mrun[u] = -3.4e38f;

    for (int tile = 0; tile < 32; ++tile) {
        const int j0 = tile * 128;
        __syncthreads();
        // stage 128 codes x 64 bf16 into LDS, chunk-swizzled
        {
            int c = t >> 1, half = t & 1;
            const ushort* src = ehi + ((size_t)g * N_E_G + j0 + c) * 64 + half * 32;
            #pragma unroll
            for (int qq = 0; qq < 4; ++qq) {
                int chunk = half * 4 + qq;
                short8 v = *(const short8*)(src + qq * 8);
                *(short8*)&eA[c * 64 + ((chunk ^ (c & 7)) * 8)] = v;
            }
        }
        __syncthreads();

        // A-frags (codes)
        short8 afrag[4][2];
        #pragma unroll
        for (int cs = 0; cs < 4; ++cs) {
            int c = chalf * 64 + cs * 16 + l15;
            #pragma unroll
            for (int ks = 0; ks < 2; ++ks) {
                int chunk = ks * 4 + quad;
                afrag[cs][ks] = *(const short8*)&eA[c * 64 + ((chunk ^ (c & 7)) * 8)];
            }
        }

        float4v acc[4][4];
        #pragma unroll
        for (int cs = 0; cs < 4; ++cs)
            #pragma unroll
            for (int u = 0; u < 4; ++u) {
                float4v zz = {0.f, 0.f, 0.f, 0.f};
                acc[cs][u] = __builtin_amdgcn_mfma_f32_16x16x32_bf16(
                                 afrag[cs][0], bfrag[u][0], zz, 0, 0, 0);
                acc[cs][u] = __builtin_amdgcn_mfma_f32_16x16x32_bf16(
                                 afrag[cs][1], bfrag[u][1], acc[cs][u], 0, 0, 0);
            }

        // epilogue: running max per query + guaranteed candidate capture
        #pragma unroll
        for (int u = 0; u < 4; ++u) {
            float m = acc[0][u][0];
            #pragma unroll
            for (int cs = 0; cs < 4; ++cs)
                #pragma unroll
                for (int r = 0; r < 4; ++r) m = fmaxf(m, acc[cs][u][r]);
            float m2 = fmaxf(m, __shfl_xor(m, 16, 64));
            float m4 = fmaxf(m2, __shfl_xor(m2, 32, 64));
            Mrun[u] = fmaxf(Mrun[u], m4);
            float thr = Mrun[u] - TAU;
            if (m >= thr) {                       // rare
                int ql = qhalf * 64 + u * 16 + l15;
                #pragma unroll
                for (int cs = 0; cs < 4; ++cs)
                    #pragma unroll
                    for (int r = 0; r < 4; ++r)
                        if (acc[cs][u][r] >= thr) {
                            int cidx = j0 + chalf * 64 + cs * 16 + quad * 4 + r;
                            int slot = atomicAdd(&cnt[ql], 1);
                            if (slot < CAP) cand[ql * CAP + slot] = cidx;
                        }
            }
        }
    }
    __syncthreads();

    // exact fp32 rescore (same sequential fma order as the round-1 kernel)
    if (t < 128) {
        int q = q0 + t;
        float za[64];
        const float4v* zp = (const float4v*)(znr + ((size_t)g * NQ + q) * 64);
        #pragma unroll
        for (int i = 0; i < 16; ++i) {
            float4v v = zp[i];
            za[i*4+0] = v[0]; za[i*4+1] = v[1]; za[i*4+2] = v[2]; za[i*4+3] = v[3];
        }
        int nc = cnt[t]; if (nc > CAP) nc = CAP;
        float best = -3.4e38f; int bk = 0x7fffffff;
        for (int s = 0; s < nc; ++s) {
            int c = cand[t * CAP + s];
            const float* ev = en + ((size_t)g * N_E_G + c) * 64;
            float a = 0.f;
            #pragma unroll
            for (int k = 0; k < 64; ++k) a = fmaf(za[k], ev[k], a);
            float d = 2.f * a - en2[g * N_E_G + c];
            if (d > best || (d == best && c < bk)) { best = d; bk = c; }
        }
        if (bk == 0x7fffffff) bk = 0;
        bks[t] = bk;
        out[OFF_IDX + (size_t)q * 4 + g] = (float)bk;
        if (g == 3) { idx3[q] = bk; atomicAdd(&hist[bk], 1); }
    }
    __syncthreads();

    // quant write, coalesced along hw
    for (int i = t; i < 128 * 64; i += 256) {
        int d = i >> 7, m = i & 127;
        int n = q0 + m, b = n >> 10, hw = n & 1023;
        out[OFF_QUANT + (size_t)b * 262144 + (size_t)(g * 64 + d) * 1024 + hw] =
            en[((size_t)g * N_E_G + bks[m]) * 64 + d];
    }
}

// ---------------------------------------------------------------------------
__global__ void fill_zero_kernel(float* __restrict__ out) {
    const long n  = OFF_IDX - OFF_VQLOSS;      // 67,108,877
    const long n4 = n >> 2;
    float4v* p4 = (float4v*)(out + OFF_VQLOSS);
    long i = (long)blockIdx.x * blockDim.x + threadIdx.x;
    long stride = (long)gridDim.x * blockDim.x;
    float4v z = {0.f, 0.f, 0.f, 0.f};
    for (long j = i; j < n4; j += stride) p4[j] = z;
    if (i == 0) {
        float* p = out + OFF_VQLOSS;
        for (long j = n4 * 4; j < n; ++j) p[j] = 0.f;
    }
}

__global__ void scatter_ones_kernel(const int* __restrict__ idx3,
                                    float* __restrict__ out) {
    int r = blockIdx.x * blockDim.x + threadIdx.x;
    if (r < NQ) out[OFF_MINENC + (size_t)r * N_E_G + idx3[r]] = 1.0f;
}

__global__ void perplexity_kernel(const int* __restrict__ hist,
                                  float* __restrict__ out) {
    __shared__ float s[256];
    int t = threadIdx.x;
    float acc = 0.f;
    for (int k = t; k < N_E_G; k += 256) {
        float p = (float)hist[k] * (1.0f / 16384.0f);
        acc += p * logf(p + 1e-10f);
    }
    s[t] = acc;
    __syncthreads();
    for (int o = 128; o; o >>= 1) {
        if (t < o) s[t] += s[t + o];
        __syncthreads();
    }
    if (t == 0) out[OFF_PERP] = expf(-s[0]);
}

// ---------------------------------------------------------------------------
extern "C" void kernel_launch(void* const* d_in, const int* in_sizes, int n_in,
                              void* d_out, int out_size, void* d_ws, size_t ws_size,
                              hipStream_t stream) {
    const float* z_groups = (const float*)d_in[0];
    const float* emb      = (const float*)d_in[1];
    float* out = (float*)d_out;
    float* ws  = (float*)d_ws;

    float*  en   = ws + WS_EN;
    float*  en2  = ws + WS_EN2;
    ushort* ehi  = (ushort*)(ws + WS_ENHI);
    float*  znr  = ws + WS_ZNR;
    ushort* zhi  = (ushort*)(ws + WS_ZHI);
    int*    hist = (int*)(ws + WS_HIST);
    int*    idx3 = (int*)(ws + WS_IDX3);

    fill_zero_kernel<<<4096, 256, 0, stream>>>(out);
    norm_emb_kernel<<<N_E / 4, 256, 0, stream>>>(emb, en, en2, ehi);
    norm_z_kernel<<<dim3(NQ / 256, GROUPS), 256, 0, stream>>>(z_groups, znr, zhi);
    hipMemsetAsync(hist, 0, N_E_G * sizeof(int), stream);

    vq_cand_kernel<<<dim3(NQ / 128, GROUPS), 256, 0, stream>>>(
        zhi, ehi, znr, en, en2, out, idx3, hist);

    scatter_ones_kernel<<<NQ / 256, 256, 0, stream>>>(idx3, out);
    perplexity_kernel<<<1, 256, 0, stream>>>(hist, out);
}

// Round 3
// 432.686 us; speedup vs baseline: 1.7756x; 1.1116x over previous
//
#include <hip/hip_runtime.h>
#include <hip/hip_bf16.h>
#include <math.h>

// Problem constants
#define N_E      16384
#define E_DIM    64
#define GROUPS   4
#define N_E_G    4096
#define NQ       16384     // B*H*W query vectors

// Output layout (element offsets into d_out, float32)
#define OFF_QUANT   0L
#define OFF_VQLOSS  4194304L
#define OFF_PERP    4194316L
#define OFF_MINENC  4194317L
#define OFF_IDX     71303181L

// Workspace layout (element offsets into d_ws as float*/int*)
#define WS_EN     0L          // normalized emb fp32 [4][4096][64]
#define WS_EN2    1048576L    // |e|^2 per code [16384]
#define WS_ENHI   1064960L    // bf16(en) ushort [4][4096][64] -> 524288 floats
#define WS_ZNR    1589248L    // normalized z fp32 [g][q][64]
#define WS_ZHI    5783552L    // bf16(zn) ushort [g][q][64] -> 2097152 floats
#define WS_HIST   7880704L    // int[4096]

typedef float  float4v  __attribute__((ext_vector_type(4)));
typedef short  short8   __attribute__((ext_vector_type(8)));

static __device__ __forceinline__ ushort f2bf(float x) {
    union { __hip_bfloat16 h; ushort u; } cv; cv.h = __float2bfloat16(x);
    return cv.u;
}

// ---------------------------------------------------------------------------
// K0: normalize embedding (one wave per code): en fp32, en2, en_hi bf16
__global__ void norm_emb_kernel(const float* __restrict__ emb,
                                float* __restrict__ en, float* __restrict__ en2,
                                ushort* __restrict__ ehi) {
    int gid  = blockIdx.x * blockDim.x + threadIdx.x;
    int code = gid >> 6;
    int lane = threadIdx.x & 63;
    if (code >= N_E) return;
    float x = emb[code * 64 + lane];
    float ss = x * x;
    #pragma unroll
    for (int off = 32; off; off >>= 1) ss += __shfl_xor(ss, off, 64);
    float v = x / fmaxf(sqrtf(ss), 1e-12f);
    en[code * 64 + lane]  = v;
    ehi[code * 64 + lane] = f2bf(v);
    float s2 = v * v;
    #pragma unroll
    for (int off = 32; off; off >>= 1) s2 += __shfl_xor(s2, off, 64);
    if (lane == 0) en2[code] = s2;
}

// ---------------------------------------------------------------------------
// K1: single-pass normalize z via 64x64 LDS tile. Reads z once (coalesced),
// writes znr fp32 + zhi bf16 transposed (coalesced). Per-query sum is
// sequential over d (bit-identical to the verified round-2 ordering).
__global__ void norm_z_kernel(const float* __restrict__ z,
                              float* __restrict__ znr, ushort* __restrict__ zhi) {
    __shared__ float tile[64 * 65];   // [d][nl], pad to kill bank conflicts
    __shared__ float rden[64];

    const int g  = blockIdx.y;
    const int n0 = blockIdx.x * 64;   // 64 queries, all within one b
    const int t  = threadIdx.x;
    const int b  = n0 >> 10, hw0 = n0 & 1023;
    const float* src = z + (size_t)b * 262144 + (size_t)g * 65536 + hw0;

    for (int i = t; i < 4096; i += 256) {
        int d = i >> 6, nl = i & 63;
        tile[d * 65 + nl] = src[(size_t)d * 1024 + nl];
    }
    __syncthreads();

    if (t < 64) {
        float ss = 0.f;
        for (int d = 0; d < 64; ++d) {
            float x = tile[d * 65 + t];
            ss = fmaf(x, x, ss);
        }
        rden[t] = fmaxf(sqrtf(ss), 1e-12f);
    }
    __syncthreads();

    for (int i = t; i < 4096; i += 256) {
        int q = i >> 6, d = i & 63;
        float v = tile[d * 65 + q] / rden[q];
        size_t o = ((size_t)g * NQ + n0 + q) * 64 + d;
        znr[o] = v;
        zhi[o] = f2bf(v);
    }
}

// ---------------------------------------------------------------------------
// K2: bf16-hi MFMA candidate generation (barrier-free K-loop, A-fragments
// double-buffered from global/L2) + exact fp32 rescore + all outputs.
// TAU >= 2*E, E = worst-case |dot - bf16hi-dot| <= 2*2^-8*(1+eps) = 7.83e-3.
#define CAP  64
#define TAU  0.017f
__global__ __launch_bounds__(256, 2)
void vq_cand_kernel(const ushort* __restrict__ zhi, const ushort* __restrict__ ehi,
                    const float* __restrict__ znr, const float* __restrict__ en,
                    const float* __restrict__ en2, float* __restrict__ out,
                    int* __restrict__ hist) {
    __shared__ int cnt[128];
    __shared__ int cand[128 * CAP];   // 32 KB
    __shared__ int bks[128];

    const int g  = blockIdx.y;
    const int q0 = blockIdx.x * 128;
    const int t  = threadIdx.x;
    const int wave = t >> 6, lane = t & 63;
    const int l15 = lane & 15, quad = lane >> 4;
    const int qhalf = wave & 1, chalf = wave >> 1;

    if (t < 128) cnt[t] = 0;

    // B-frags (queries, bf16-hi), registers for the whole kernel
    short8 bfrag[4][2];
    {
        const ushort* zq = zhi + ((size_t)g * NQ + q0 + qhalf * 64 + l15) * 64 + quad * 8;
        #pragma unroll
        for (int u = 0; u < 4; ++u)
            #pragma unroll
            for (int ks = 0; ks < 2; ++ks)
                bfrag[u][ks] = *(const short8*)(zq + u * 16 * 64 + ks * 32);
    }
    __syncthreads();   // cnt ready before first capture

    // A-operand base for this lane: code row chalf*64 + l15, k-chunk quad*8
    const ushort* abase = ehi + (size_t)g * N_E_G * 64
                        + (size_t)(chalf * 64 + l15) * 64 + quad * 8;

    float Mrun[4];
    #pragma unroll
    for (int u = 0; u < 4; ++u) Mrun[u] = -3.4e38f;

    short8 afA[4][2], afB[4][2];
    #pragma unroll
    for (int cs = 0; cs < 4; ++cs)
        #pragma unroll
        for (int ks = 0; ks < 2; ++ks)
            afA[cs][ks] = *(const short8*)(abase + (size_t)(cs * 16) * 64 + ks * 32);

    auto do_tile = [&](short8 (&A)[4][2], short8 (&P)[4][2], int tile) {
        // prefetch next tile's A-fragments into P (L2-resident codebook)
        if (tile + 1 < 32) {
            const ushort* p = abase + (size_t)((tile + 1) * 128) * 64;
            #pragma unroll
            for (int cs = 0; cs < 4; ++cs)
                #pragma unroll
                for (int ks = 0; ks < 2; ++ks)
                    P[cs][ks] = *(const short8*)(p + (size_t)(cs * 16) * 64 + ks * 32);
        }
        float4v acc[4][4];
        #pragma unroll
        for (int cs = 0; cs < 4; ++cs)
            #pragma unroll
            for (int u = 0; u < 4; ++u) {
                float4v zz = {0.f, 0.f, 0.f, 0.f};
                float4v tmp = __builtin_amdgcn_mfma_f32_16x16x32_bf16(
                                  A[cs][0], bfrag[u][0], zz, 0, 0, 0);
                acc[cs][u] = __builtin_amdgcn_mfma_f32_16x16x32_bf16(
                                  A[cs][1], bfrag[u][1], tmp, 0, 0, 0);
            }
        const int j0 = tile * 128;
        #pragma unroll
        for (int u = 0; u < 4; ++u) {
            float m = acc[0][u][0];
            #pragma unroll
            for (int cs = 0; cs < 4; ++cs)
                #pragma unroll
                for (int r = 0; r < 4; ++r) m = fmaxf(m, acc[cs][u][r]);
            float m2 = fmaxf(m, __shfl_xor(m, 16, 64));
            float m4 = fmaxf(m2, __shfl_xor(m2, 32, 64));
            Mrun[u] = fmaxf(Mrun[u], m4);
            float thr = Mrun[u] - TAU;
            if (m >= thr) {                    // rare
                int ql = qhalf * 64 + u * 16 + l15;
                #pragma unroll
                for (int cs = 0; cs < 4; ++cs)
                    #pragma unroll
                    for (int r = 0; r < 4; ++r)
                        if (acc[cs][u][r] >= thr) {
                            int cidx = j0 + chalf * 64 + cs * 16 + quad * 4 + r;
                            int slot = atomicAdd(&cnt[ql], 1);
                            if (slot < CAP) cand[ql * CAP + slot] = cidx;
                        }
            }
        }
    };

    for (int tt = 0; tt < 32; tt += 2) {
        do_tile(afA, afB, tt);
        do_tile(afB, afA, tt + 1);
    }
    __syncthreads();

    // exact fp32 rescore (verified ordering/tie-break: first-wins == min idx)
    if (t < 128) {
        int q = q0 + t;
        float za[64];
        const float4v* zp = (const float4v*)(znr + ((size_t)g * NQ + q) * 64);
        #pragma unroll
        for (int i = 0; i < 16; ++i) {
            float4v v = zp[i];
            za[i*4+0] = v[0]; za[i*4+1] = v[1]; za[i*4+2] = v[2]; za[i*4+3] = v[3];
        }
        int nc = cnt[t]; if (nc > CAP) nc = CAP;
        float best = -3.4e38f; int bk = 0x7fffffff;
        for (int s = 0; s < nc; ++s) {
            int c = cand[t * CAP + s];
            const float* ev = en + ((size_t)g * N_E_G + c) * 64;
            float a = 0.f;
            #pragma unroll
            for (int k = 0; k < 64; ++k) a = fmaf(za[k], ev[k], a);
            float d = 2.f * a - en2[g * N_E_G + c];
            if (d > best || (d == best && c < bk)) { best = d; bk = c; }
        }
        if (bk == 0x7fffffff) bk = 0;
        bks[t] = bk;
        out[OFF_IDX + (size_t)q * 4 + g] = (float)bk;
        if (g == 3) {
            atomicAdd(&hist[bk], 1);
            out[OFF_MINENC + (size_t)q * N_E_G + bk] = 1.0f;   // memset'd 0 earlier
        }
    }
    __syncthreads();

    // quant write, coalesced along hw
    for (int i = t; i < 128 * 64; i += 256) {
        int d = i >> 7, m = i & 127;
        int n = q0 + m, b = n >> 10, hw = n & 1023;
        out[OFF_QUANT + (size_t)b * 262144 + (size_t)(g * 64 + d) * 1024 + hw] =
            en[((size_t)g * N_E_G + bks[m]) * 64 + d];
    }
}

// ---------------------------------------------------------------------------
__global__ void perplexity_kernel(const int* __restrict__ hist,
                                  float* __restrict__ out) {
    __shared__ float s[256];
    int t = threadIdx.x;
    float acc = 0.f;
    for (int k = t; k < N_E_G; k += 256) {
        float p = (float)hist[k] * (1.0f / 16384.0f);
        acc += p * logf(p + 1e-10f);
    }
    s[t] = acc;
    __syncthreads();
    for (int o = 128; o; o >>= 1) {
        if (t < o) s[t] += s[t + o];
        __syncthreads();
    }
    if (t == 0) out[OFF_PERP] = expf(-s[0]);
}

// ---------------------------------------------------------------------------
extern "C" void kernel_launch(void* const* d_in, const int* in_sizes, int n_in,
                              void* d_out, int out_size, void* d_ws, size_t ws_size,
                              hipStream_t stream) {
    const float* z_groups = (const float*)d_in[0];
    const float* emb      = (const float*)d_in[1];
    float* out = (float*)d_out;
    float* ws  = (float*)d_ws;

    float*  en   = ws + WS_EN;
    float*  en2  = ws + WS_EN2;
    ushort* ehi  = (ushort*)(ws + WS_ENHI);
    float*  znr  = ws + WS_ZNR;
    ushort* zhi  = (ushort*)(ws + WS_ZHI);
    int*    hist = (int*)(ws + WS_HIST);

    // zero the losses/usage/perp slot + min_encodings (268 MB) at fill-BW
    hipMemsetAsync(out + OFF_VQLOSS, 0, (OFF_IDX - OFF_VQLOSS) * sizeof(float), stream);
    hipMemsetAsync(hist, 0, N_E_G * sizeof(int), stream);

    norm_emb_kernel<<<N_E / 4, 256, 0, stream>>>(emb, en, en2, ehi);
    norm_z_kernel<<<dim3(NQ / 64, GROUPS), 256, 0, stream>>>(z_groups, znr, zhi);

    vq_cand_kernel<<<dim3(NQ / 128, GROUPS), 256, 0, stream>>>(
        zhi, ehi, znr, en, en2, out, hist);

    perplexity_kernel<<<1, 256, 0, stream>>>(hist, out);
}